// Round 13
// baseline (4851.587 us; speedup 1.0000x reference)
//
#include <hip/hip_runtime.h>
#include <hip/hip_cooperative_groups.h>

namespace cg = cooperative_groups;

// Problem geometry
#define N_ROWS 8192   // 4*2048 latents
#define N_COLS 2048   // codebook entries
#define TPB    1024   // threads per block (16 waves)

#define AGENT __HIP_MEMORY_SCOPE_AGENT

__device__ __forceinline__ double ALD(const double* p) {
  return __hip_atomic_load(p, __ATOMIC_RELAXED, AGENT);
}
__device__ __forceinline__ void AST(double* p, double v) {
  __hip_atomic_store(p, v, __ATOMIC_RELAXED, AGENT);
}

// ---------------------------------------------------------------------------
// fast f64 exp, |x| <= ~102, rel err ~2e-16 (Cody-Waite + Taylor-13)
// ---------------------------------------------------------------------------
__device__ __forceinline__ double fexp(double x) {
  const double L2E   = 1.4426950408889634074;
  const double LN2HI = 6.93147180369123816490e-01;
  const double LN2LO = 1.90821492927058770002e-10;
  double t = x * L2E;
  double n = rint(t);
  double r = __fma_rn(n, -LN2HI, x);
  r = __fma_rn(n, -LN2LO, r);
  double p = 1.6059043836821613e-10;
  p = __fma_rn(p, r, 2.08767569878681e-09);
  p = __fma_rn(p, r, 2.505210838544172e-08);
  p = __fma_rn(p, r, 2.7557319223985893e-07);
  p = __fma_rn(p, r, 2.755731922398589e-06);
  p = __fma_rn(p, r, 2.48015873015873e-05);
  p = __fma_rn(p, r, 1.9841269841269841e-04);
  p = __fma_rn(p, r, 1.3888888888888889e-03);
  p = __fma_rn(p, r, 8.333333333333333e-03);
  p = __fma_rn(p, r, 4.1666666666666664e-02);
  p = __fma_rn(p, r, 1.6666666666666666e-01);
  p = __fma_rn(p, r, 0.5);
  p = __fma_rn(p, r, 1.0);
  p = __fma_rn(p, r, 1.0);
  long long ni = (long long)n;
  double sc = __longlong_as_double((ni + 1023LL) << 52);
  return p * sc;
}

// ---------------------------------------------------------------------------
// fence-free distributed grid barrier with HANG-PROOF bounded spin.
// ---------------------------------------------------------------------------
__device__ __forceinline__ void gridbar2(unsigned* bar, unsigned& epoch,
                                         unsigned lpl, volatile unsigned* dead) {
  __syncthreads();                       // drains vmcnt(0): sc1 stores visible
  ++epoch;
  if (!*dead) {
    if (threadIdx.x == 0)
      __hip_atomic_fetch_add(&bar[(blockIdx.x & 63) << 5], 1u, __ATOMIC_RELAXED, AGENT);
    if (threadIdx.x < 64) {
      unsigned tgt = epoch * lpl;
      unsigned spins = 0;
      while (__hip_atomic_load(&bar[threadIdx.x << 5], __ATOMIC_RELAXED, AGENT) < tgt) {
        __builtin_amdgcn_s_sleep(2);
        if (++spins > (1u << 20)) { *dead = 1u; break; }
      }
    }
  }
  __syncthreads();
}

// ---------------------------------------------------------------------------
// per-row squared norms (wave per row, 128 cols)
// ---------------------------------------------------------------------------
__global__ void rowsq_kernel(const float* __restrict__ p, float* __restrict__ o, int nrows) {
  int w = (int)((blockIdx.x * blockDim.x + threadIdx.x) >> 6);
  int lane = threadIdx.x & 63;
  if (w >= nrows) return;
  float2 v = ((const float2*)(p + (size_t)w * 128))[lane];
  float s = v.x * v.x + v.y * v.y;
  #pragma unroll
  for (int off = 32; off; off >>= 1) s += __shfl_down(s, off);
  if (lane == 0) o[w] = s;
}

// ---------------------------------------------------------------------------
// d[i,k] = xx[i] + cc[k] - 2*x.c  (64x64 tile, K=128), + per-block min/max
// ---------------------------------------------------------------------------
__global__ __launch_bounds__(256) void dist_kernel(
    const float* __restrict__ x, const float* __restrict__ cb,
    const float* __restrict__ xx, const float* __restrict__ cc,
    float* __restrict__ dbuf, float* __restrict__ minp, float* __restrict__ maxp)
{
  __shared__ float xs[64][129];
  __shared__ float csh[64][129];
  const int bi = blockIdx.y;
  const int bk = blockIdx.x;
  const int t  = threadIdx.x;

  const float4* xg = (const float4*)(x  + (size_t)bi * 64 * 128);
  const float4* cg4 = (const float4*)(cb + (size_t)bk * 64 * 128);
  #pragma unroll
  for (int i = 0; i < 8; ++i) {
    int e = t + i * 256;
    int r = e >> 5, c = e & 31;
    float4 v = xg[e];
    xs[r][4*c+0] = v.x; xs[r][4*c+1] = v.y; xs[r][4*c+2] = v.z; xs[r][4*c+3] = v.w;
    float4 w = cg4[e];
    csh[r][4*c+0] = w.x; csh[r][4*c+1] = w.y; csh[r][4*c+2] = w.z; csh[r][4*c+3] = w.w;
  }
  __syncthreads();

  const int rg = t >> 4, cgi = t & 15;
  float acc[4][4];
  #pragma unroll
  for (int i = 0; i < 4; ++i)
    #pragma unroll
    for (int j = 0; j < 4; ++j) acc[i][j] = 0.f;

  for (int k = 0; k < 128; ++k) {
    float a0 = xs[rg*4+0][k], a1 = xs[rg*4+1][k], a2 = xs[rg*4+2][k], a3 = xs[rg*4+3][k];
    float b0 = csh[cgi*4+0][k], b1 = csh[cgi*4+1][k], b2 = csh[cgi*4+2][k], b3 = csh[cgi*4+3][k];
    acc[0][0] += a0*b0; acc[0][1] += a0*b1; acc[0][2] += a0*b2; acc[0][3] += a0*b3;
    acc[1][0] += a1*b0; acc[1][1] += a1*b1; acc[1][2] += a1*b2; acc[1][3] += a1*b3;
    acc[2][0] += a2*b0; acc[2][1] += a2*b1; acc[2][2] += a2*b2; acc[2][3] += a2*b3;
    acc[3][0] += a3*b0; acc[3][1] += a3*b1; acc[3][2] += a3*b2; acc[3][3] += a3*b3;
  }

  float lmin = 1e30f, lmax = -1e30f;
  #pragma unroll
  for (int i = 0; i < 4; ++i) {
    int gi = bi*64 + rg*4 + i;
    float xxv = xx[gi];
    float dv[4];
    #pragma unroll
    for (int j = 0; j < 4; ++j) {
      int gk = bk*64 + cgi*4 + j;
      dv[j] = (xxv + cc[gk]) - 2.f * acc[i][j];
      lmin = fminf(lmin, dv[j]); lmax = fmaxf(lmax, dv[j]);
    }
    float4 o = make_float4(dv[0], dv[1], dv[2], dv[3]);
    *((float4*)(dbuf + (size_t)gi * N_COLS + bk*64 + cgi*4)) = o;
  }

  #pragma unroll
  for (int off = 32; off; off >>= 1) {
    lmin = fminf(lmin, __shfl_down(lmin, off));
    lmax = fmaxf(lmax, __shfl_down(lmax, off));
  }
  __shared__ float rmn[4], rmx[4];
  int wave = t >> 6, lane = t & 63;
  if (lane == 0) { rmn[wave] = lmin; rmx[wave] = lmax; }
  __syncthreads();
  if (t == 0) {
    float mn = fminf(fminf(rmn[0], rmn[1]), fminf(rmn[2], rmn[3]));
    float mx = fmaxf(fmaxf(rmx[0], rmx[1]), fmaxf(rmx[2], rmx[3]));
    int bid = bi * gridDim.x + bk;
    minp[bid] = mn; maxp[bid] = mx;
  }
}

// ---------------------------------------------------------------------------
// reduce 4096 min/max partials -> mid, amp (f32, exactly like reference)
// ---------------------------------------------------------------------------
__global__ __launch_bounds__(1024) void minmax_reduce_kernel(
    const float* __restrict__ minp, const float* __restrict__ maxp, float* __restrict__ sc)
{
  int t = threadIdx.x;
  float mn = 1e30f, mx = -1e30f;
  for (int i = t; i < 4096; i += 1024) { mn = fminf(mn, minp[i]); mx = fmaxf(mx, maxp[i]); }
  #pragma unroll
  for (int off = 32; off; off >>= 1) {
    mn = fminf(mn, __shfl_down(mn, off));
    mx = fmaxf(mx, __shfl_down(mx, off));
  }
  __shared__ float smn[16], smx[16];
  int wave = t >> 6, lane = t & 63;
  if (lane == 0) { smn[wave] = mn; smx[wave] = mx; }
  __syncthreads();
  if (t == 0) {
    for (int w = 1; w < 16; ++w) { mn = fminf(mn, smn[w]); mx = fmaxf(mx, smx[w]); }
    float mid = (mx + mn) * 0.5f;
    float amp = mx - mid + 1e-5f;
    sc[0] = mid; sc[1] = amp;
  }
}

// ---------------------------------------------------------------------------
// center in place: dc = (d - mid) / amp, rounded to f32 (matches reference)
// ---------------------------------------------------------------------------
__global__ void center_kernel(float* __restrict__ dbuf, const float* __restrict__ sc) {
  float mid = sc[0], amp = sc[1];
  size_t stride = (size_t)gridDim.x * blockDim.x;
  for (size_t i = blockIdx.x * blockDim.x + threadIdx.x; i < (size_t)N_ROWS * N_COLS; i += stride) {
    float dv = dbuf[i];
    dbuf[i] = (dv - mid) / amp;
  }
}

// ---------------------------------------------------------------------------
// Round-13 Sinkhorn (= round-12 design; r12 never ran, infra died pre-push):
// 512 blocks x 16 rows (2/CU), 4-row groups. Only f[4] (8 VGPRs) lives
// across the block reduce — fits the allocator's observed 32-VGPR choice
// with no spills. exp recomputed from registers in colsum (2x exp/elem/sweep,
// ~7.5 us VALU, hidden under memory). Precentered dc.
// ---------------------------------------------------------------------------
__global__ __launch_bounds__(TPB, 8)
void sinkhorn12_kernel(
    const float* __restrict__ dc, double* __restrict__ part,
    double* __restrict__ vg, double* __restrict__ lossp,
    const float* __restrict__ x, const float* __restrict__ cb,
    float* __restrict__ out, unsigned* __restrict__ bar)
{
  constexpr int NB  = 512;             // blocks
  constexpr int RPB = 16;              // rows per block
  constexpr int CPB = 4;               // cols per block in vreduce
  constexpr unsigned LPL = NB / 64;    // barrier arrivals per line (=8)

  __shared__ double sh[2048];          // vg stage / epilogue scratch (16 KB)
  __shared__ double red[16][4][16];    // rowsum cross-wave partials (8 KB)
  __shared__ double ush[4];
  __shared__ int    idx_loc[RPB];
  __shared__ unsigned deadf;
  const int b = blockIdx.x, t = threadIdx.x;
  const int lane = t & 63, wave = t >> 6;
  const int row0 = b * RPB;
  const int c0i = 2 * t;               // this thread's two columns
  const float2* dc2 = (const float2*)dc;
  unsigned epoch = 0;
  double* redf = &red[0][0][0];
  if (t == 0) deadf = 0u;              // ordered by first gridbar2 entry sync

  // ---- vreduce: 512 partials -> v_k = 1/(K*colsum), 4 cols per block
  auto vreduce = [&]() {
    int c = t & (CPB - 1), p = t / CPB;         // p in 0..255
    int col = b * CPB + c;
    double s = ALD(part + ((size_t)p << 11) + col)
             + ALD(part + ((size_t)(p + 256) << 11) + col);
    #pragma unroll
    for (int off = CPB; off < 64; off <<= 1) s += __shfl_down(s, off);
    if (lane < CPB) redf[wave * CPB + lane] = s;
    __syncthreads();
    if (t < CPB) {
      double a = 0.0;
      #pragma unroll
      for (int w = 0; w < 16; ++w) a += redf[w * CPB + t];
      AST(vg + b * CPB + t, 1.0 / (2048.0 * a));
    }
  };

  // ---- prologue sweep: u = 1 -> column partials -> v^1
  {
    double c0 = 0.0, c1 = 0.0;
    for (int r = 0; r < RPB; ++r) {
      float2 f = dc2[((size_t)(row0 + r) << 10) + t];
      c0 += fexp((double)f.x * -100.0);
      c1 += fexp((double)f.y * -100.0);
    }
    AST(part + ((size_t)b << 11) + c0i, c0);
    AST(part + ((size_t)b << 11) + c0i + 1, c1);
  }
  gridbar2(bar, epoch, LPL, &deadf);
  vreduce();
  gridbar2(bar, epoch, LPL, &deadf);

  // ---- 99 fused sweeps: 4 groups of 4 rows; only f[4] crosses the reduce
  for (int it = 1; it < 100; ++it) {
    double vx = ALD(vg + c0i), vy = ALD(vg + c0i + 1);
    double c0 = 0.0, c1 = 0.0;
    #pragma unroll
    for (int g = 0; g < 4; ++g) {
      const int rbase = row0 + g * 4;
      float2 f[4];
      #pragma unroll
      for (int q = 0; q < 4; ++q) f[q] = dc2[((size_t)(rbase + q) << 10) + t];
      // rowsum partials (per-q immediate reduce keeps live set tiny)
      #pragma unroll
      for (int q = 0; q < 4; ++q) {
        double e0 = fexp((double)f[q].x * -100.0);
        double e1 = fexp((double)f[q].y * -100.0);
        double s = __fma_rn(vx, e0, vy * e1);
        s += __shfl_down(s, 32);
        s += __shfl_down(s, 16);
        if (lane < 16) red[wave][q][lane] = s;
      }
      __syncthreads();
      if (t < 64) {
        int q = t >> 4;
        double a = 0.0;
        #pragma unroll
        for (int w = 0; w < 16; ++w) a += red[w][q][t & 15];
        a += __shfl_down(a, 8); a += __shfl_down(a, 4);
        a += __shfl_down(a, 2); a += __shfl_down(a, 1);
        if ((t & 15) == 0) ush[q] = 1.0 / (8192.0 * a);
      }
      __syncthreads();
      // colsum accumulate: re-exp from the f registers (no reload)
      #pragma unroll
      for (int q = 0; q < 4; ++q) {
        double e0 = fexp((double)f[q].x * -100.0);
        double e1 = fexp((double)f[q].y * -100.0);
        double u = ush[q];
        c0 = __fma_rn(u, e0, c0);
        c1 = __fma_rn(u, e1, c1);
      }
    }
    AST(part + ((size_t)b << 11) + c0i, c0);
    AST(part + ((size_t)b << 11) + c0i + 1, c1);
    gridbar2(bar, epoch, LPL, &deadf);
    vreduce();
    gridbar2(bar, epoch, LPL, &deadf);
  }

  // ---- argmax_k v^100_k * E[i,k]: one wave per row
  {
    sh[t] = ALD(vg + t);
    sh[t + 1024] = ALD(vg + t + 1024);
    __syncthreads();
    int r = row0 + wave;                 // 16 waves = 16 rows
    const float* rp = dc + ((size_t)r << 11);
    double bv = -1.0; int bk = 0;
    for (int j = 0; j < 32; ++j) {
      int col = lane + (j << 6);
      double val = sh[col] * fexp((double)rp[col] * -100.0);
      if (val > bv) { bv = val; bk = col; }
    }
    #pragma unroll
    for (int off = 32; off; off >>= 1) {
      double ov = __shfl_down(bv, off);
      int ok = __shfl_down(bk, off);
      if (ov > bv || (ov == bv && ok < bk)) { bv = ov; bk = ok; }
    }
    if (lane == 0) {
      idx_loc[wave] = bk;
      out[1048577 + r] = (float)bk;
    }
    __syncthreads();
  }

  // ---- gather x_q, straight-through out, loss partial
  double lsum = 0.0;
  #pragma unroll
  for (int c = 0; c < 2; ++c) {
    int e = (c << 10) + t;               // 0..2047 = 16 rows x 128
    int r = e >> 7, d = e & 127;
    int k = idx_loc[r];
    float cv = cb[(k << 7) + d];
    size_t gi = (((size_t)(row0 + r)) << 7) + d;
    float xv = x[gi];
    float diff = cv - xv;
    out[gi] = xv + diff;
    lsum += (double)diff * (double)diff;
  }
  #pragma unroll
  for (int off = 32; off; off >>= 1) lsum += __shfl_down(lsum, off);
  __syncthreads();
  if (lane == 0) sh[wave] = lsum;
  __syncthreads();
  if (t == 0) {
    double s = 0.0;
    for (int w = 0; w < 16; ++w) s += sh[w];
    AST(lossp + b, s);
  }
  gridbar2(bar, epoch, LPL, &deadf);
  if (b == 0) {
    double ls = (t < NB) ? ALD(lossp + t) : 0.0;
    #pragma unroll
    for (int off = 32; off; off >>= 1) ls += __shfl_down(ls, off);
    __syncthreads();
    if (lane == 0) sh[wave] = ls;
    __syncthreads();
    if (t == 0) {
      double s = 0.0;
      for (int w = 0; w < 16; ++w) s += sh[w];
      double L = s / 1048576.0;
      out[1048576] = (float)(0.2 * L + 0.8 * L);
    }
  }
}

// ---------------------------------------------------------------------------
// FALLBACK A (round-8, proven): 256 blocks x 32 rows, used if 2/CU won't fit.
// ---------------------------------------------------------------------------
__global__ __launch_bounds__(TPB, 4)
void sinkhorn8_kernel(
    const float* __restrict__ dc, double* __restrict__ part,
    double* __restrict__ vg, double* __restrict__ lossp,
    const float* __restrict__ x, const float* __restrict__ cb,
    float* __restrict__ out, unsigned* __restrict__ bar)
{
  constexpr int NB  = 256;
  constexpr int RPB = 32;
  constexpr int CPB = 8;
  constexpr int G   = 4;
  constexpr unsigned LPL = NB / 64;
  constexpr int P   = 1024 / CPB;

  __shared__ double sh[2048];
  __shared__ double red[16][8][16];
  __shared__ double ush[8];
  __shared__ int    idx_loc[RPB];
  __shared__ unsigned deadf;
  const int b = blockIdx.x, t = threadIdx.x;
  const int lane = t & 63, wave = t >> 6;
  const int row0 = b * RPB;
  const int c0i = 2 * t;
  const float2* dc2 = (const float2*)dc;
  unsigned epoch = 0;
  double* redf = &red[0][0][0];
  if (t == 0) deadf = 0u;

  auto vreduce = [&]() {
    int c = t & (CPB - 1), p = t / CPB;
    int col = b * CPB + c;
    double s = ALD(part + ((size_t)p << 11) + col)
             + ALD(part + ((size_t)(p + P) << 11) + col);
    #pragma unroll
    for (int off = CPB; off < 64; off <<= 1) s += __shfl_down(s, off);
    if (lane < CPB) redf[wave * CPB + lane] = s;
    __syncthreads();
    if (t < CPB) {
      double a = 0.0;
      #pragma unroll
      for (int w = 0; w < 16; ++w) a += redf[w * CPB + t];
      AST(vg + b * CPB + t, 1.0 / (2048.0 * a));
    }
  };

  {
    double c0 = 0.0, c1 = 0.0;
    for (int g = 0; g < G; ++g) {
      const int rbase = row0 + g * 8;
      #pragma unroll
      for (int q = 0; q < 8; ++q) {
        float2 f = dc2[((size_t)(rbase + q) << 10) + t];
        c0 += fexp((double)f.x * -100.0);
        c1 += fexp((double)f.y * -100.0);
      }
    }
    AST(part + ((size_t)b << 11) + c0i, c0);
    AST(part + ((size_t)b << 11) + c0i + 1, c1);
  }
  gridbar2(bar, epoch, LPL, &deadf);
  vreduce();
  gridbar2(bar, epoch, LPL, &deadf);

  for (int it = 1; it < 100; ++it) {
    double vx = ALD(vg + c0i), vy = ALD(vg + c0i + 1);
    double c0 = 0.0, c1 = 0.0;
    float2 fc[8];
    #pragma unroll
    for (int q = 0; q < 8; ++q) fc[q] = dc2[((size_t)(row0 + q) << 10) + t];
    #pragma unroll
    for (int g = 0; g < G; ++g) {
      double e0[8], e1[8];
      #pragma unroll
      for (int q = 0; q < 8; ++q) {
        e0[q] = fexp((double)fc[q].x * -100.0);
        e1[q] = fexp((double)fc[q].y * -100.0);
      }
      float2 fn[8];
      if (g < G - 1) {
        const int nbase = row0 + (g + 1) * 8;
        #pragma unroll
        for (int q = 0; q < 8; ++q) fn[q] = dc2[((size_t)(nbase + q) << 10) + t];
      }
      double s[8];
      #pragma unroll
      for (int q = 0; q < 8; ++q) s[q] = __fma_rn(vx, e0[q], vy * e1[q]);
      #pragma unroll
      for (int q = 0; q < 8; ++q) {
        s[q] += __shfl_down(s[q], 32);
        s[q] += __shfl_down(s[q], 16);
      }
      if (lane < 16) {
        #pragma unroll
        for (int q = 0; q < 8; ++q) red[wave][q][lane] = s[q];
      }
      __syncthreads();
      if (t < 128) {
        int q = t >> 4;
        double a = 0.0;
        #pragma unroll
        for (int w = 0; w < 16; ++w) a += red[w][q][t & 15];
        a += __shfl_down(a, 8); a += __shfl_down(a, 4);
        a += __shfl_down(a, 2); a += __shfl_down(a, 1);
        if ((t & 15) == 0) ush[q] = 1.0 / (8192.0 * a);
      }
      __syncthreads();
      #pragma unroll
      for (int q = 0; q < 8; ++q) {
        double u = ush[q];
        c0 = __fma_rn(u, e0[q], c0);
        c1 = __fma_rn(u, e1[q], c1);
      }
      if (g < G - 1) {
        #pragma unroll
        for (int q = 0; q < 8; ++q) fc[q] = fn[q];
      }
    }
    AST(part + ((size_t)b << 11) + c0i, c0);
    AST(part + ((size_t)b << 11) + c0i + 1, c1);
    gridbar2(bar, epoch, LPL, &deadf);
    vreduce();
    gridbar2(bar, epoch, LPL, &deadf);
  }

  {
    sh[t] = ALD(vg + t);
    sh[t + 1024] = ALD(vg + t + 1024);
    __syncthreads();
    #pragma unroll
    for (int rr = 0; rr < RPB / 16; ++rr) {
      int r = row0 + rr * 16 + wave;
      const float* rp = dc + ((size_t)r << 11);
      double bv = -1.0; int bk = 0;
      for (int j = 0; j < 32; ++j) {
        int col = lane + (j << 6);
        double val = sh[col] * fexp((double)rp[col] * -100.0);
        if (val > bv) { bv = val; bk = col; }
      }
      #pragma unroll
      for (int off = 32; off; off >>= 1) {
        double ov = __shfl_down(bv, off);
        int ok = __shfl_down(bk, off);
        if (ov > bv || (ov == bv && ok < bk)) { bv = ov; bk = ok; }
      }
      if (lane == 0) {
        idx_loc[rr * 16 + wave] = bk;
        out[1048577 + r] = (float)bk;
      }
    }
    __syncthreads();
  }

  double lsum = 0.0;
  #pragma unroll
  for (int c = 0; c < G; ++c) {
    int e = (c << 10) + t;
    int r = e >> 7, d = e & 127;
    int k = idx_loc[r];
    float cv = cb[(k << 7) + d];
    size_t gi = (((size_t)(row0 + r)) << 7) + d;
    float xv = x[gi];
    float diff = cv - xv;
    out[gi] = xv + diff;
    lsum += (double)diff * (double)diff;
  }
  #pragma unroll
  for (int off = 32; off; off >>= 1) lsum += __shfl_down(lsum, off);
  __syncthreads();
  if (lane == 0) sh[wave] = lsum;
  __syncthreads();
  if (t == 0) {
    double s = 0.0;
    for (int w = 0; w < 16; ++w) s += sh[w];
    AST(lossp + b, s);
  }
  gridbar2(bar, epoch, LPL, &deadf);
  if (b == 0) {
    double ls = (t < NB) ? ALD(lossp + t) : 0.0;
    #pragma unroll
    for (int off = 32; off; off >>= 1) ls += __shfl_down(ls, off);
    __syncthreads();
    if (lane == 0) sh[wave] = ls;
    __syncthreads();
    if (t == 0) {
      double s = 0.0;
      for (int w = 0; w < 16; ++w) s += sh[w];
      double L = s / 1048576.0;
      out[1048576] = (float)(0.2 * L + 0.8 * L);
    }
  }
}

// ---------------------------------------------------------------------------
// FALLBACK B (round-1) sinkhorn, ockl grid sync (used only if ws too small)
// ---------------------------------------------------------------------------
__global__ __launch_bounds__(TPB) void sinkhorn_kernel(
    const float* __restrict__ dc, double* __restrict__ part,
    double* __restrict__ vg, double* __restrict__ lossp,
    const float* __restrict__ x, const float* __restrict__ cb,
    float* __restrict__ out)
{
  cg::grid_group grid = cg::this_grid();
  __shared__ double sh[2048];
  __shared__ double u_loc[32];
  __shared__ int idx_loc[32];
  const int b = blockIdx.x, t = threadIdx.x;
  const int lane = t & 63, wave = t >> 6;
  const int row0 = b * 32;
  const double C = -1.0 / 0.01;

  if (t < 32) u_loc[t] = 1.0;
  __syncthreads();

  for (int it = 0; it < 100; ++it) {
    double a0 = 0.0, a1 = 0.0;
    for (int r = 0; r < 32; ++r) {
      double u = u_loc[r];
      const float* rp = dc + ((size_t)(row0 + r) << 11);
      a0 += u * fexp((double)rp[t] * C);
      a1 += u * fexp((double)rp[t + 1024] * C);
    }
    part[((size_t)b << 11) + t] = a0;
    part[((size_t)b << 11) + t + 1024] = a1;
    grid.sync();
    {
      int kk = t & 7, p = t >> 3;
      int col = (b << 3) + kk;
      double s = part[((size_t)p << 11) + col] + part[((size_t)(p + 128) << 11) + col];
      sh[(kk << 7) + p] = s;
      __syncthreads();
      for (int off = 64; off >= 1; off >>= 1) {
        if (p < off) sh[(kk << 7) + p] += sh[(kk << 7) + p + off];
        __syncthreads();
      }
      if (t < 8) vg[(b << 3) + t] = 1.0 / (2048.0 * sh[t << 7]);
    }
    grid.sync();

    for (int i = t; i < 2048; i += TPB) sh[i] = vg[i];
    __syncthreads();
    #pragma unroll
    for (int rr = 0; rr < 2; ++rr) {
      int r = wave + (rr << 4);
      const float* rp = dc + ((size_t)(row0 + r) << 11);
      double s = 0.0;
      for (int j = 0; j < 32; ++j) {
        int k = lane + (j << 6);
        s += sh[k] * fexp((double)rp[k] * C);
      }
      #pragma unroll
      for (int off = 32; off; off >>= 1) s += __shfl_down(s, off);
      if (lane == 0) u_loc[r] = 1.0 / (8192.0 * s);
    }
    __syncthreads();
  }

  #pragma unroll
  for (int rr = 0; rr < 2; ++rr) {
    int r = wave + (rr << 4);
    const float* rp = dc + ((size_t)(row0 + r) << 11);
    double bv = -1.0; int bk = 0;
    for (int j = 0; j < 32; ++j) {
      int k = lane + (j << 6);
      double val = sh[k] * fexp((double)rp[k] * C);
      if (val > bv) { bv = val; bk = k; }
    }
    #pragma unroll
    for (int off = 32; off; off >>= 1) {
      double ov = __shfl_down(bv, off);
      int ok = __shfl_down(bk, off);
      if (ov > bv || (ov == bv && ok < bk)) { bv = ov; bk = ok; }
    }
    if (lane == 0) {
      idx_loc[r] = bk;
      out[1048577 + row0 + r] = (float)bk;
    }
  }
  __syncthreads();

  double lsum = 0.0;
  #pragma unroll
  for (int c = 0; c < 4; ++c) {
    int e = (c << 10) + t;
    int r = e >> 7, d = e & 127;
    int k = idx_loc[r];
    float cv = cb[(k << 7) + d];
    size_t gi = (((size_t)(row0 + r)) << 7) + d;
    float xv = x[gi];
    float diff = cv - xv;
    out[gi] = xv + diff;
    lsum += (double)diff * (double)diff;
  }
  #pragma unroll
  for (int off = 32; off; off >>= 1) lsum += __shfl_down(lsum, off);
  __syncthreads();
  if (lane == 0) sh[wave] = lsum;
  __syncthreads();
  if (t == 0) {
    double s = 0.0;
    for (int w = 0; w < 16; ++w) s += sh[w];
    lossp[b] = s;
  }
  grid.sync();
  if (b == 0 && t == 0) {
    double s = 0.0;
    for (int i = 0; i < 256; ++i) s += lossp[i];
    double L = s / 1048576.0;
    out[1048576] = (float)(0.2 * L + 0.8 * L);
  }
}

// ---------------------------------------------------------------------------
extern "C" void kernel_launch(void* const* d_in, const int* in_sizes, int n_in,
                              void* d_out, int out_size, void* d_ws, size_t ws_size,
                              hipStream_t stream) {
  const float* x  = (const float*)d_in[0];
  const float* cb = (const float*)d_in[1];
  float* out = (float*)d_out;
  char* ws = (char*)d_ws;

  const size_t oDC    = 0;                   // 67108864 (centered distances)
  const size_t oPART  = 67108864;            //  8388608 (512 x 2048 x 8B)
  const size_t oVG    = 75497472;            //    16384
  const size_t oLOSSP = 75513856;            //     4096 (512 doubles)
  const size_t oBAR   = 75517952;            //     8192
  const size_t oXX    = 75526144;            //    32768
  const size_t oCC    = 75558912;            //     8192
  const size_t oMINP  = 75567104;            //    16384
  const size_t oMAXP  = 75583488;            //    16384
  const size_t oSCP   = 75599872;            //       64
  const size_t NEED   = 75599936;

  if (ws_size >= NEED) {
    float*    dcb   = (float*) (ws + oDC);
    double*   part  = (double*)(ws + oPART);
    double*   vgv   = (double*)(ws + oVG);
    double*   lossp = (double*)(ws + oLOSSP);
    unsigned* bar   = (unsigned*)(ws + oBAR);
    float*    xx    = (float*) (ws + oXX);
    float*    cc    = (float*) (ws + oCC);
    float*    minp  = (float*) (ws + oMINP);
    float*    maxp  = (float*) (ws + oMAXP);
    float*    scp   = (float*) (ws + oSCP);

    rowsq_kernel<<<2048, 256, 0, stream>>>(x, xx, N_ROWS);
    rowsq_kernel<<<512, 256, 0, stream>>>(cb, cc, N_COLS);
    dim3 dg(32, 128);
    dist_kernel<<<dg, 256, 0, stream>>>(x, cb, xx, cc, dcb, minp, maxp);
    minmax_reduce_kernel<<<1, 1024, 0, stream>>>(minp, maxp, scp);
    center_kernel<<<2048, 256, 0, stream>>>(dcb, scp);
    hipMemsetAsync(bar, 0, 8192, stream);

    void* args[] = {(void*)&dcb, (void*)&part, (void*)&vgv, (void*)&lossp,
                    (void*)&x, (void*)&cb, (void*)&out, (void*)&bar};

    int occ2 = 0;
    hipError_t qe = hipOccupancyMaxActiveBlocksPerMultiprocessor(
        &occ2, sinkhorn12_kernel, TPB, 0);
    bool ok = false;
    if (qe == hipSuccess && occ2 >= 2) {
      hipError_t le = hipLaunchCooperativeKernel((void*)sinkhorn12_kernel,
                                                 dim3(512), dim3(TPB), args, 0, stream);
      ok = (le == hipSuccess);
    }
    if (!ok) {
      hipLaunchCooperativeKernel((void*)sinkhorn8_kernel,
                                 dim3(256), dim3(TPB), args, 0, stream);
    }
  } else {
    // FALLBACK: round-1 layout (needs ~71.4 MB)
    float*  dcbuf = (float*) (ws);
    double* part  = (double*)(ws + 67108864);
    double* vgv   = (double*)(ws + 71303168);
    double* lossp = (double*)(ws + 71319552);
    float*  xx    = (float*) (ws + 71321600);
    float*  cc    = (float*) (ws + 71354368);
    float*  minp  = (float*) (ws + 71362560);
    float*  maxp  = (float*) (ws + 71378944);
    float*  scp   = (float*) (ws + 71395328);

    rowsq_kernel<<<2048, 256, 0, stream>>>(x, xx, N_ROWS);
    rowsq_kernel<<<512, 256, 0, stream>>>(cb, cc, N_COLS);
    dim3 dg(32, 128);
    dist_kernel<<<dg, 256, 0, stream>>>(x, cb, xx, cc, dcbuf, minp, maxp);
    minmax_reduce_kernel<<<1, 1024, 0, stream>>>(minp, maxp, scp);
    center_kernel<<<2048, 256, 0, stream>>>(dcbuf, scp);

    void* args[] = {(void*)&dcbuf, (void*)&part, (void*)&vgv, (void*)&lossp,
                    (void*)&x, (void*)&cb, (void*)&out};
    hipLaunchCooperativeKernel((void*)sinkhorn_kernel, dim3(256), dim3(TPB),
                               args, 0, stream);
  }
}

// Round 16
// 2781.509 us; speedup vs baseline: 1.7442x; 1.7442x over previous
//
#include <hip/hip_runtime.h>
#include <hip/hip_cooperative_groups.h>

namespace cg = cooperative_groups;

// Problem geometry
#define N_ROWS 8192   // 4*2048 latents
#define N_COLS 2048   // codebook entries
#define TPB    1024   // threads per block (16 waves)

#define AGENT __HIP_MEMORY_SCOPE_AGENT

__device__ __forceinline__ double ALD(const double* p) {
  return __hip_atomic_load(p, __ATOMIC_RELAXED, AGENT);
}
__device__ __forceinline__ void AST(double* p, double v) {
  __hip_atomic_store(p, v, __ATOMIC_RELAXED, AGENT);
}

// ---------------------------------------------------------------------------
// fast f64 exp, |x| <= ~102, rel err ~2e-16 (Cody-Waite + Taylor-13)
// ---------------------------------------------------------------------------
__device__ __forceinline__ double fexp(double x) {
  const double L2E   = 1.4426950408889634074;
  const double LN2HI = 6.93147180369123816490e-01;
  const double LN2LO = 1.90821492927058770002e-10;
  double t = x * L2E;
  double n = rint(t);
  double r = __fma_rn(n, -LN2HI, x);
  r = __fma_rn(n, -LN2LO, r);
  double p = 1.6059043836821613e-10;
  p = __fma_rn(p, r, 2.08767569878681e-09);
  p = __fma_rn(p, r, 2.505210838544172e-08);
  p = __fma_rn(p, r, 2.7557319223985893e-07);
  p = __fma_rn(p, r, 2.755731922398589e-06);
  p = __fma_rn(p, r, 2.48015873015873e-05);
  p = __fma_rn(p, r, 1.9841269841269841e-04);
  p = __fma_rn(p, r, 1.3888888888888889e-03);
  p = __fma_rn(p, r, 8.333333333333333e-03);
  p = __fma_rn(p, r, 4.1666666666666664e-02);
  p = __fma_rn(p, r, 1.6666666666666666e-01);
  p = __fma_rn(p, r, 0.5);
  p = __fma_rn(p, r, 1.0);
  p = __fma_rn(p, r, 1.0);
  long long ni = (long long)n;
  double sc = __longlong_as_double((ni + 1023LL) << 52);
  return p * sc;
}

// ---------------------------------------------------------------------------
// fence-free distributed grid barrier with HANG-PROOF bounded spin.
// ---------------------------------------------------------------------------
__device__ __forceinline__ void gridbar2(unsigned* bar, unsigned& epoch,
                                         unsigned lpl, volatile unsigned* dead) {
  __syncthreads();                       // drains vmcnt(0): sc1 stores visible
  ++epoch;
  if (!*dead) {
    if (threadIdx.x == 0)
      __hip_atomic_fetch_add(&bar[(blockIdx.x & 63) << 5], 1u, __ATOMIC_RELAXED, AGENT);
    if (threadIdx.x < 64) {
      unsigned tgt = epoch * lpl;
      unsigned spins = 0;
      while (__hip_atomic_load(&bar[threadIdx.x << 5], __ATOMIC_RELAXED, AGENT) < tgt) {
        __builtin_amdgcn_s_sleep(2);
        if (++spins > (1u << 20)) { *dead = 1u; break; }
      }
    }
  }
  __syncthreads();
}

// ---------------------------------------------------------------------------
// per-row squared norms (wave per row, 128 cols)
// ---------------------------------------------------------------------------
__global__ void rowsq_kernel(const float* __restrict__ p, float* __restrict__ o, int nrows) {
  int w = (int)((blockIdx.x * blockDim.x + threadIdx.x) >> 6);
  int lane = threadIdx.x & 63;
  if (w >= nrows) return;
  float2 v = ((const float2*)(p + (size_t)w * 128))[lane];
  float s = v.x * v.x + v.y * v.y;
  #pragma unroll
  for (int off = 32; off; off >>= 1) s += __shfl_down(s, off);
  if (lane == 0) o[w] = s;
}

// ---------------------------------------------------------------------------
// d[i,k] = xx[i] + cc[k] - 2*x.c  (64x64 tile, K=128), + per-block min/max
// ---------------------------------------------------------------------------
__global__ __launch_bounds__(256) void dist_kernel(
    const float* __restrict__ x, const float* __restrict__ cb,
    const float* __restrict__ xx, const float* __restrict__ cc,
    float* __restrict__ dbuf, float* __restrict__ minp, float* __restrict__ maxp)
{
  __shared__ float xs[64][129];
  __shared__ float csh[64][129];
  const int bi = blockIdx.y;
  const int bk = blockIdx.x;
  const int t  = threadIdx.x;

  const float4* xg = (const float4*)(x  + (size_t)bi * 64 * 128);
  const float4* cg4 = (const float4*)(cb + (size_t)bk * 64 * 128);
  #pragma unroll
  for (int i = 0; i < 8; ++i) {
    int e = t + i * 256;
    int r = e >> 5, c = e & 31;
    float4 v = xg[e];
    xs[r][4*c+0] = v.x; xs[r][4*c+1] = v.y; xs[r][4*c+2] = v.z; xs[r][4*c+3] = v.w;
    float4 w = cg4[e];
    csh[r][4*c+0] = w.x; csh[r][4*c+1] = w.y; csh[r][4*c+2] = w.z; csh[r][4*c+3] = w.w;
  }
  __syncthreads();

  const int rg = t >> 4, cgi = t & 15;
  float acc[4][4];
  #pragma unroll
  for (int i = 0; i < 4; ++i)
    #pragma unroll
    for (int j = 0; j < 4; ++j) acc[i][j] = 0.f;

  for (int k = 0; k < 128; ++k) {
    float a0 = xs[rg*4+0][k], a1 = xs[rg*4+1][k], a2 = xs[rg*4+2][k], a3 = xs[rg*4+3][k];
    float b0 = csh[cgi*4+0][k], b1 = csh[cgi*4+1][k], b2 = csh[cgi*4+2][k], b3 = csh[cgi*4+3][k];
    acc[0][0] += a0*b0; acc[0][1] += a0*b1; acc[0][2] += a0*b2; acc[0][3] += a0*b3;
    acc[1][0] += a1*b0; acc[1][1] += a1*b1; acc[1][2] += a1*b2; acc[1][3] += a1*b3;
    acc[2][0] += a2*b0; acc[2][1] += a2*b1; acc[2][2] += a2*b2; acc[2][3] += a2*b3;
    acc[3][0] += a3*b0; acc[3][1] += a3*b1; acc[3][2] += a3*b2; acc[3][3] += a3*b3;
  }

  float lmin = 1e30f, lmax = -1e30f;
  #pragma unroll
  for (int i = 0; i < 4; ++i) {
    int gi = bi*64 + rg*4 + i;
    float xxv = xx[gi];
    float dv[4];
    #pragma unroll
    for (int j = 0; j < 4; ++j) {
      int gk = bk*64 + cgi*4 + j;
      dv[j] = (xxv + cc[gk]) - 2.f * acc[i][j];
      lmin = fminf(lmin, dv[j]); lmax = fmaxf(lmax, dv[j]);
    }
    float4 o = make_float4(dv[0], dv[1], dv[2], dv[3]);
    *((float4*)(dbuf + (size_t)gi * N_COLS + bk*64 + cgi*4)) = o;
  }

  #pragma unroll
  for (int off = 32; off; off >>= 1) {
    lmin = fminf(lmin, __shfl_down(lmin, off));
    lmax = fmaxf(lmax, __shfl_down(lmax, off));
  }
  __shared__ float rmn[4], rmx[4];
  int wave = t >> 6, lane = t & 63;
  if (lane == 0) { rmn[wave] = lmin; rmx[wave] = lmax; }
  __syncthreads();
  if (t == 0) {
    float mn = fminf(fminf(rmn[0], rmn[1]), fminf(rmn[2], rmn[3]));
    float mx = fmaxf(fmaxf(rmx[0], rmx[1]), fmaxf(rmx[2], rmx[3]));
    int bid = bi * gridDim.x + bk;
    minp[bid] = mn; maxp[bid] = mx;
  }
}

// ---------------------------------------------------------------------------
// reduce 4096 min/max partials -> mid, amp (f32, exactly like reference)
// ---------------------------------------------------------------------------
__global__ __launch_bounds__(1024) void minmax_reduce_kernel(
    const float* __restrict__ minp, const float* __restrict__ maxp, float* __restrict__ sc)
{
  int t = threadIdx.x;
  float mn = 1e30f, mx = -1e30f;
  for (int i = t; i < 4096; i += 1024) { mn = fminf(mn, minp[i]); mx = fmaxf(mx, maxp[i]); }
  #pragma unroll
  for (int off = 32; off; off >>= 1) {
    mn = fminf(mn, __shfl_down(mn, off));
    mx = fmaxf(mx, __shfl_down(mx, off));
  }
  __shared__ float smn[16], smx[16];
  int wave = t >> 6, lane = t & 63;
  if (lane == 0) { smn[wave] = mn; smx[wave] = mx; }
  __syncthreads();
  if (t == 0) {
    for (int w = 1; w < 16; ++w) { mn = fminf(mn, smn[w]); mx = fmaxf(mx, smx[w]); }
    float mid = (mx + mn) * 0.5f;
    float amp = mx - mid + 1e-5f;
    sc[0] = mid; sc[1] = amp;
  }
}

// ---------------------------------------------------------------------------
// center in place: dc = (d - mid) / amp, rounded to f32 (matches reference)
// ---------------------------------------------------------------------------
__global__ void center_kernel(float* __restrict__ dbuf, const float* __restrict__ sc) {
  float mid = sc[0], amp = sc[1];
  size_t stride = (size_t)gridDim.x * blockDim.x;
  for (size_t i = blockIdx.x * blockDim.x + threadIdx.x; i < (size_t)N_ROWS * N_COLS; i += stride) {
    float dv = dbuf[i];
    dbuf[i] = (dv - mid) / amp;
  }
}

// ---------------------------------------------------------------------------
// Round-16 Sinkhorn (= round-14 design; r14/r15 never ran, infra died
// pre-push both times): EXACT round-6 structure (the 3143 us best: fused
// sweep, RPB-row blocks, G groups of 8 rows, 4 syncthreads/sweep, f[8] held
// across both uses) with ONE change: dc precentered (per-use f32 div gone).
// ---------------------------------------------------------------------------
template<int RPB>
__global__ __launch_bounds__(TPB, (RPB == 16) ? 8 : 4)
void sinkhorn14_kernel(
    const float* __restrict__ dc, double* __restrict__ part,
    double* __restrict__ vg, double* __restrict__ lossp,
    const float* __restrict__ x, const float* __restrict__ cb,
    float* __restrict__ out, unsigned* __restrict__ bar)
{
  constexpr int NB  = N_ROWS / RPB;    // 512 or 256 blocks
  constexpr int CPB = 2048 / NB;       // 4 or 8 cols per block in vreduce
  constexpr int G   = RPB / 8;         // groups of 8 rows
  constexpr unsigned LPL = NB / 64;    // barrier arrivals per line
  constexpr int P   = 1024 / CPB;      // threads per column in vreduce

  __shared__ double sh[2048];          // vg stage / epilogue scratch
  __shared__ double red[16][8][16];    // rowsum cross-wave partials (16 KB)
  __shared__ double ush[8];
  __shared__ int    idx_loc[RPB];
  __shared__ unsigned deadf;
  const int b = blockIdx.x, t = threadIdx.x;
  const int lane = t & 63, wave = t >> 6;
  const int row0 = b * RPB;
  const int c0i = 2 * t;               // this thread's two columns
  const float2* dc2 = (const float2*)dc;
  unsigned epoch = 0;
  double* redf = &red[0][0][0];
  if (t == 0) deadf = 0u;              // ordered by first gridbar2 entry sync

  // ---- vreduce: NB partials -> v_k = 1/(K*colsum), CPB cols per block
  auto vreduce = [&]() {
    int c = t & (CPB - 1), p = t / CPB;
    int col = b * CPB + c;
    double s = ALD(part + ((size_t)p << 11) + col)
             + ALD(part + ((size_t)(p + P) << 11) + col);
    #pragma unroll
    for (int off = CPB; off < 64; off <<= 1) s += __shfl_down(s, off);
    if (lane < CPB) redf[wave * CPB + lane] = s;
    __syncthreads();
    if (t < CPB) {
      double a = 0.0;
      #pragma unroll
      for (int w = 0; w < 16; ++w) a += redf[w * CPB + t];
      AST(vg + b * CPB + t, 1.0 / (2048.0 * a));
    }
  };

  // ---- prologue sweep: u = 1 -> column partials -> v^1
  {
    double c0 = 0.0, c1 = 0.0;
    for (int g = 0; g < G; ++g) {
      const int rbase = row0 + g * 8;
      #pragma unroll
      for (int q = 0; q < 8; ++q) {
        float2 f = dc2[((size_t)(rbase + q) << 10) + t];
        c0 += fexp((double)f.x * -100.0);
        c1 += fexp((double)f.y * -100.0);
      }
    }
    AST(part + ((size_t)b << 11) + c0i, c0);
    AST(part + ((size_t)b << 11) + c0i + 1, c1);
  }
  gridbar2(bar, epoch, LPL, &deadf);
  vreduce();
  gridbar2(bar, epoch, LPL, &deadf);

  // ---- 99 fused sweeps: one memory pass; f[8] held for the colsum re-exp.
  for (int it = 1; it < 100; ++it) {
    double vx = ALD(vg + c0i), vy = ALD(vg + c0i + 1);
    double c0 = 0.0, c1 = 0.0;
    for (int g = 0; g < G; ++g) {
      const int rbase = row0 + g * 8;
      float2 f[8];
      #pragma unroll
      for (int q = 0; q < 8; ++q) f[q] = dc2[((size_t)(rbase + q) << 10) + t];
      double s[8];
      #pragma unroll
      for (int q = 0; q < 8; ++q) {
        double e0 = fexp((double)f[q].x * -100.0);
        double e1 = fexp((double)f[q].y * -100.0);
        s[q] = __fma_rn(vx, e0, vy * e1);
      }
      #pragma unroll
      for (int q = 0; q < 8; ++q) {
        s[q] += __shfl_down(s[q], 32);
        s[q] += __shfl_down(s[q], 16);
      }
      if (lane < 16) {
        #pragma unroll
        for (int q = 0; q < 8; ++q) red[wave][q][lane] = s[q];
      }
      __syncthreads();
      if (t < 128) {
        int q = t >> 4;
        double a = 0.0;
        #pragma unroll
        for (int w = 0; w < 16; ++w) a += red[w][q][t & 15];
        a += __shfl_down(a, 8); a += __shfl_down(a, 4);
        a += __shfl_down(a, 2); a += __shfl_down(a, 1);
        if ((t & 15) == 0) ush[q] = 1.0 / (8192.0 * a);
      }
      __syncthreads();
      // colsum accumulate from registers (re-exp, no reload)
      #pragma unroll
      for (int q = 0; q < 8; ++q) {
        double e0 = fexp((double)f[q].x * -100.0);
        double e1 = fexp((double)f[q].y * -100.0);
        double u = ush[q];
        c0 = __fma_rn(u, e0, c0);
        c1 = __fma_rn(u, e1, c1);
      }
    }
    AST(part + ((size_t)b << 11) + c0i, c0);
    AST(part + ((size_t)b << 11) + c0i + 1, c1);
    gridbar2(bar, epoch, LPL, &deadf);
    vreduce();
    gridbar2(bar, epoch, LPL, &deadf);
  }

  // ---- argmax_k v^100_k * E[i,k]: one wave per row, no per-row syncs
  {
    sh[t] = ALD(vg + t);
    sh[t + 1024] = ALD(vg + t + 1024);
    __syncthreads();
    #pragma unroll
    for (int rr = 0; rr < RPB / 16; ++rr) {
      int r = row0 + rr * 16 + wave;
      const float* rp = dc + ((size_t)r << 11);
      double bv = -1.0; int bk = 0;
      for (int j = 0; j < 32; ++j) {
        int col = lane + (j << 6);
        double val = sh[col] * fexp((double)rp[col] * -100.0);
        if (val > bv) { bv = val; bk = col; }
      }
      #pragma unroll
      for (int off = 32; off; off >>= 1) {
        double ov = __shfl_down(bv, off);
        int ok = __shfl_down(bk, off);
        if (ov > bv || (ov == bv && ok < bk)) { bv = ov; bk = ok; }
      }
      if (lane == 0) {
        idx_loc[rr * 16 + wave] = bk;
        out[1048577 + r] = (float)bk;
      }
    }
    __syncthreads();
  }

  // ---- gather x_q, straight-through out, loss partial
  double lsum = 0.0;
  #pragma unroll
  for (int c = 0; c < G; ++c) {
    int e = (c << 10) + t;               // 0..RPB*128-1
    int r = e >> 7, d = e & 127;
    int k = idx_loc[r];
    float cv = cb[(k << 7) + d];
    size_t gi = (((size_t)(row0 + r)) << 7) + d;
    float xv = x[gi];
    float diff = cv - xv;
    out[gi] = xv + diff;
    lsum += (double)diff * (double)diff;
  }
  #pragma unroll
  for (int off = 32; off; off >>= 1) lsum += __shfl_down(lsum, off);
  __syncthreads();
  if (lane == 0) sh[wave] = lsum;
  __syncthreads();
  if (t == 0) {
    double s = 0.0;
    for (int w = 0; w < 16; ++w) s += sh[w];
    AST(lossp + b, s);
  }
  gridbar2(bar, epoch, LPL, &deadf);
  if (b == 0) {
    double ls = (t < NB) ? ALD(lossp + t) : 0.0;
    #pragma unroll
    for (int off = 32; off; off >>= 1) ls += __shfl_down(ls, off);
    __syncthreads();
    if (lane == 0) sh[wave] = ls;
    __syncthreads();
    if (t == 0) {
      double s = 0.0;
      for (int w = 0; w < 16; ++w) s += sh[w];
      double L = s / 1048576.0;
      out[1048576] = (float)(0.2 * L + 0.8 * L);
    }
  }
}

// ---------------------------------------------------------------------------
// FALLBACK B (round-1) sinkhorn, ockl grid sync (used only if ws too small)
// ---------------------------------------------------------------------------
__global__ __launch_bounds__(TPB) void sinkhorn_kernel(
    const float* __restrict__ dc, double* __restrict__ part,
    double* __restrict__ vg, double* __restrict__ lossp,
    const float* __restrict__ x, const float* __restrict__ cb,
    float* __restrict__ out)
{
  cg::grid_group grid = cg::this_grid();
  __shared__ double sh[2048];
  __shared__ double u_loc[32];
  __shared__ int idx_loc[32];
  const int b = blockIdx.x, t = threadIdx.x;
  const int lane = t & 63, wave = t >> 6;
  const int row0 = b * 32;
  const double C = -1.0 / 0.01;

  if (t < 32) u_loc[t] = 1.0;
  __syncthreads();

  for (int it = 0; it < 100; ++it) {
    double a0 = 0.0, a1 = 0.0;
    for (int r = 0; r < 32; ++r) {
      double u = u_loc[r];
      const float* rp = dc + ((size_t)(row0 + r) << 11);
      a0 += u * fexp((double)rp[t] * C);
      a1 += u * fexp((double)rp[t + 1024] * C);
    }
    part[((size_t)b << 11) + t] = a0;
    part[((size_t)b << 11) + t + 1024] = a1;
    grid.sync();
    {
      int kk = t & 7, p = t >> 3;
      int col = (b << 3) + kk;
      double s = part[((size_t)p << 11) + col] + part[((size_t)(p + 128) << 11) + col];
      sh[(kk << 7) + p] = s;
      __syncthreads();
      for (int off = 64; off >= 1; off >>= 1) {
        if (p < off) sh[(kk << 7) + p] += sh[(kk << 7) + p + off];
        __syncthreads();
      }
      if (t < 8) vg[(b << 3) + t] = 1.0 / (2048.0 * sh[t << 7]);
    }
    grid.sync();

    for (int i = t; i < 2048; i += TPB) sh[i] = vg[i];
    __syncthreads();
    #pragma unroll
    for (int rr = 0; rr < 2; ++rr) {
      int r = wave + (rr << 4);
      const float* rp = dc + ((size_t)(row0 + r) << 11);
      double s = 0.0;
      for (int j = 0; j < 32; ++j) {
        int k = lane + (j << 6);
        s += sh[k] * fexp((double)rp[k] * C);
      }
      #pragma unroll
      for (int off = 32; off; off >>= 1) s += __shfl_down(s, off);
      if (lane == 0) u_loc[r] = 1.0 / (8192.0 * s);
    }
    __syncthreads();
  }

  #pragma unroll
  for (int rr = 0; rr < 2; ++rr) {
    int r = wave + (rr << 4);
    const float* rp = dc + ((size_t)(row0 + r) << 11);
    double bv = -1.0; int bk = 0;
    for (int j = 0; j < 32; ++j) {
      int k = lane + (j << 6);
      double val = sh[k] * fexp((double)rp[k] * C);
      if (val > bv) { bv = val; bk = k; }
    }
    #pragma unroll
    for (int off = 32; off; off >>= 1) {
      double ov = __shfl_down(bv, off);
      int ok = __shfl_down(bk, off);
      if (ov > bv || (ov == bv && ok < bk)) { bv = ov; bk = ok; }
    }
    if (lane == 0) {
      idx_loc[r] = bk;
      out[1048577 + row0 + r] = (float)bk;
    }
  }
  __syncthreads();

  double lsum = 0.0;
  #pragma unroll
  for (int c = 0; c < 4; ++c) {
    int e = (c << 10) + t;
    int r = e >> 7, d = e & 127;
    int k = idx_loc[r];
    float cv = cb[(k << 7) + d];
    size_t gi = (((size_t)(row0 + r)) << 7) + d;
    float xv = x[gi];
    float diff = cv - xv;
    out[gi] = xv + diff;
    lsum += (double)diff * (double)diff;
  }
  #pragma unroll
  for (int off = 32; off; off >>= 1) lsum += __shfl_down(lsum, off);
  __syncthreads();
  if (lane == 0) sh[wave] = lsum;
  __syncthreads();
  if (t == 0) {
    double s = 0.0;
    for (int w = 0; w < 16; ++w) s += sh[w];
    lossp[b] = s;
  }
  grid.sync();
  if (b == 0 && t == 0) {
    double s = 0.0;
    for (int i = 0; i < 256; ++i) s += lossp[i];
    double L = s / 1048576.0;
    out[1048576] = (float)(0.2 * L + 0.8 * L);
  }
}

// ---------------------------------------------------------------------------
extern "C" void kernel_launch(void* const* d_in, const int* in_sizes, int n_in,
                              void* d_out, int out_size, void* d_ws, size_t ws_size,
                              hipStream_t stream) {
  const float* x  = (const float*)d_in[0];
  const float* cb = (const float*)d_in[1];
  float* out = (float*)d_out;
  char* ws = (char*)d_ws;

  const size_t oDC    = 0;                   // 67108864 (centered distances)
  const size_t oPART  = 67108864;            //  8388608 (512 x 2048 x 8B)
  const size_t oVG    = 75497472;            //    16384
  const size_t oLOSSP = 75513856;            //     4096 (512 doubles)
  const size_t oBAR   = 75517952;            //     8192
  const size_t oXX    = 75526144;            //    32768
  const size_t oCC    = 75558912;            //     8192
  const size_t oMINP  = 75567104;            //    16384
  const size_t oMAXP  = 75583488;            //    16384
  const size_t oSCP   = 75599872;            //       64
  const size_t NEED   = 75599936;

  if (ws_size >= NEED) {
    float*    dcb   = (float*) (ws + oDC);
    double*   part  = (double*)(ws + oPART);
    double*   vgv   = (double*)(ws + oVG);
    double*   lossp = (double*)(ws + oLOSSP);
    unsigned* bar   = (unsigned*)(ws + oBAR);
    float*    xx    = (float*) (ws + oXX);
    float*    cc    = (float*) (ws + oCC);
    float*    minp  = (float*) (ws + oMINP);
    float*    maxp  = (float*) (ws + oMAXP);
    float*    scp   = (float*) (ws + oSCP);

    rowsq_kernel<<<2048, 256, 0, stream>>>(x, xx, N_ROWS);
    rowsq_kernel<<<512, 256, 0, stream>>>(cb, cc, N_COLS);
    dim3 dg(32, 128);
    dist_kernel<<<dg, 256, 0, stream>>>(x, cb, xx, cc, dcb, minp, maxp);
    minmax_reduce_kernel<<<1, 1024, 0, stream>>>(minp, maxp, scp);
    center_kernel<<<2048, 256, 0, stream>>>(dcb, scp);
    hipMemsetAsync(bar, 0, 8192, stream);

    void* args[] = {(void*)&dcb, (void*)&part, (void*)&vgv, (void*)&lossp,
                    (void*)&x, (void*)&cb, (void*)&out, (void*)&bar};

    int occ2 = 0;
    hipError_t qe = hipOccupancyMaxActiveBlocksPerMultiprocessor(
        &occ2, sinkhorn14_kernel<16>, TPB, 0);
    bool ok = false;
    if (qe == hipSuccess && occ2 >= 2) {
      hipError_t le = hipLaunchCooperativeKernel((void*)sinkhorn14_kernel<16>,
                                                 dim3(512), dim3(TPB), args, 0, stream);
      ok = (le == hipSuccess);
    }
    if (!ok) {
      hipLaunchCooperativeKernel((void*)sinkhorn14_kernel<32>,
                                 dim3(256), dim3(TPB), args, 0, stream);
    }
  } else {
    // FALLBACK: round-1 layout (needs ~71.4 MB)
    float*  dcbuf = (float*) (ws);
    double* part  = (double*)(ws + 67108864);
    double* vgv   = (double*)(ws + 71303168);
    double* lossp = (double*)(ws + 71319552);
    float*  xx    = (float*) (ws + 71321600);
    float*  cc    = (float*) (ws + 71354368);
    float*  minp  = (float*) (ws + 71362560);
    float*  maxp  = (float*) (ws + 71378944);
    float*  scp   = (float*) (ws + 71395328);

    rowsq_kernel<<<2048, 256, 0, stream>>>(x, xx, N_ROWS);
    rowsq_kernel<<<512, 256, 0, stream>>>(cb, cc, N_COLS);
    dim3 dg(32, 128);
    dist_kernel<<<dg, 256, 0, stream>>>(x, cb, xx, cc, dcbuf, minp, maxp);
    minmax_reduce_kernel<<<1, 1024, 0, stream>>>(minp, maxp, scp);
    center_kernel<<<2048, 256, 0, stream>>>(dcbuf, scp);

    void* args[] = {(void*)&dcbuf, (void*)&part, (void*)&vgv, (void*)&lossp,
                    (void*)&x, (void*)&cb, (void*)&out};
    hipLaunchCooperativeKernel((void*)sinkhorn_kernel, dim3(256), dim3(TPB),
                               args, 0, stream);
  }
}